// Round 2
// baseline (874.953 us; speedup 1.0000x reference)
//
#include <hip/hip_runtime.h>
#include <stdint.h>

// Problem constants (match reference)
#define D_DIM 4096
#define O_DIM 4096
#define M_DIM 8192      // B*S = 4*2048
#define TOPK_K 2048
#define NMASKS 100

typedef __attribute__((ext_vector_type(8))) short bf16x8;
typedef __attribute__((ext_vector_type(4))) float f32x4;

__device__ __forceinline__ unsigned short f2bf(float f) {
    unsigned u = __float_as_uint(f);
    return (unsigned short)((u + 0x7FFFu + ((u >> 16) & 1u)) >> 16);
}

// ---------------- control path ----------------

__global__ void init_ws_kernel(float* f, int* counts) {
    int i = threadIdx.x;
    for (int j = i; j < D_DIM; j += blockDim.x) f[j] = 0.0f;
    if (i < NMASKS) counts[i] = 0;
}

// Detect stored_masks encoding: raw bytes (numpy bool) vs int32-widened.
// Byte encoding at ~50% density => words with value > 1 are certain.
__global__ void detect_mask_fmt_kernel(const unsigned* __restrict__ raw,
                                       int* __restrict__ flag) {
    __shared__ int anybig;
    if (threadIdx.x == 0) anybig = 0;
    __syncthreads();
    int big = 0;
    for (int i = threadIdx.x; i < 1024; i += blockDim.x)
        if (raw[i] > 1u) big = 1;
    if (big) atomicOr(&anybig, 1);
    __syncthreads();
    if (threadIdx.x == 0) *flag = anybig;   // 1 = byte-encoded, 0 = int32
}

__global__ void normalize_masks_kernel(const void* __restrict__ raw,
                                       const int* __restrict__ flag,
                                       unsigned char* __restrict__ out) {
    int n = NMASKS * D_DIM;
    int fmt = *flag;
    int stride = gridDim.x * blockDim.x;
    for (int i = blockIdx.x * blockDim.x + threadIdx.x; i < n; i += stride) {
        unsigned char v;
        if (fmt) v = ((const unsigned char*)raw)[i] ? 1 : 0;
        else     v = ((const int*)raw)[i] ? 1 : 0;
        out[i] = v;
    }
}

// f[d] = mean over rows 0..pb of x[0,:,d]
__global__ void reduce_mean_kernel(const float* __restrict__ x,
                                   const int* __restrict__ pb_ptr,
                                   float* __restrict__ f) {
    int d = blockIdx.x * blockDim.x + threadIdx.x;   // 16 blocks * 256 = 4096
    int rows = *pb_ptr + 1;
    float s = 0.0f;
    for (int r = blockIdx.y; r < rows; r += gridDim.y)
        s += x[(size_t)r * D_DIM + d];
    atomicAdd(&f[d], s * (1.0f / (float)rows));
}

// single block, 1024 threads: kth-largest |f| via binary search on float bits,
// then mask[perm[d]] = 1 for selected d.
__global__ void topk_mask_kernel(const float* __restrict__ f,
                                 const int* __restrict__ perm,
                                 unsigned char* __restrict__ mask) {
    __shared__ unsigned bits[D_DIM];
    __shared__ int scount;
    int tid = threadIdx.x;
    for (int i = tid; i < D_DIM; i += 1024) {
        bits[i] = __float_as_uint(f[i]) & 0x7FFFFFFFu;
        mask[i] = 0;
    }
    __syncthreads();
    unsigned lo = 0u, hi = 0x7F800001u;
    while (hi - lo > 1u) {
        unsigned mid = lo + ((hi - lo) >> 1);
        if (tid == 0) scount = 0;
        __syncthreads();
        int c = 0;
        for (int i = tid; i < D_DIM; i += 1024) c += (bits[i] >= mid) ? 1 : 0;
        atomicAdd(&scount, c);
        __syncthreads();
        if (scount >= TOPK_K) lo = mid; else hi = mid;
        __syncthreads();   // protect scount read vs next-iter reset
    }
    for (int i = tid; i < D_DIM; i += 1024)
        if (bits[i] >= lo) mask[perm[i]] = 1;
}

// one block per stored mask: popcount overlap
__global__ void overlap_kernel(const unsigned char* __restrict__ mask,
                               const unsigned char* __restrict__ stored,
                               int* __restrict__ counts) {
    int m = blockIdx.x;
    int tid = threadIdx.x;                      // 256 threads * 16B = 4096B
    const uint4* a = (const uint4*)mask;
    const uint4* b = (const uint4*)(stored + (size_t)m * D_DIM);
    uint4 va = a[tid], vb = b[tid];
    int c = __popc((va.x & vb.x) & 0x01010101u) + __popc((va.y & vb.y) & 0x01010101u)
          + __popc((va.z & vb.z) & 0x01010101u) + __popc((va.w & vb.w) & 0x01010101u);
    for (int off = 32; off; off >>= 1) c += __shfl_down(c, off);
    if ((tid & 63) == 0) atomicAdd(&counts[m], c);
}

// single block: argmax over counts, gate, write final mask as float 0/1
__global__ void gate_kernel(const int* __restrict__ counts,
                            const unsigned char* __restrict__ stored,
                            float* __restrict__ fmask) {
    __shared__ int bestc, besti;
    if (threadIdx.x == 0) {
        int bc = -1, bi = 0;
        for (int m = 0; m < NMASKS; m++)
            if (counts[m] > bc) { bc = counts[m]; bi = m; }
        bestc = bc; besti = bi;
    }
    __syncthreads();
    bool gate = ((float)bestc / (float)TOPK_K) >= 0.6f;
    const unsigned char* sm = stored + (size_t)besti * D_DIM;
    for (int i = threadIdx.x; i < D_DIM; i += blockDim.x)
        fmask[i] = (gate && sm[i]) ? 1.0f : 0.0f;
}

// ---------------- conversions ----------------

__global__ void cvt_x_kernel(const float4* __restrict__ x,
                             ushort4* __restrict__ xb, int ngroups) {
    int stride = gridDim.x * blockDim.x;
    for (int j = blockIdx.x * blockDim.x + threadIdx.x; j < ngroups; j += stride) {
        float4 v = x[j];
        ushort4 o = { f2bf(v.x), f2bf(v.y), f2bf(v.z), f2bf(v.w) };
        xb[j] = o;
    }
}

// W_eff = W + fmask[d]*W_new, cast to bf16
__global__ void cvt_w_kernel(const float4* __restrict__ w,
                             const float4* __restrict__ nw,
                             const float4* __restrict__ fmask,
                             ushort4* __restrict__ wb, int ngroups) {
    int stride = gridDim.x * blockDim.x;
    for (int j = blockIdx.x * blockDim.x + threadIdx.x; j < ngroups; j += stride) {
        float4 a = w[j], b = nw[j], mk = fmask[j & (D_DIM / 4 - 1)];
        ushort4 o = { f2bf(a.x + mk.x * b.x), f2bf(a.y + mk.y * b.y),
                      f2bf(a.z + mk.z * b.z), f2bf(a.w + mk.w * b.w) };
        wb[j] = o;
    }
}

// ---------------- GEMM: C[m][n] = sum_k A[m][k]*B[n][k], bf16 in, f32 out ----
// m97 structure: 128x128 tile, BK=64, 4 waves (2x2), 16x16x32 MFMA,
// global_load_lds width=16, XCD-bijective swizzle.

__global__ __launch_bounds__(256) void gemm_bf16_kernel(
    const unsigned short* __restrict__ A,   // [M][K]
    const unsigned short* __restrict__ B,   // [N][K]
    float* __restrict__ C) {
    constexpr int K = D_DIM, N = O_DIM;
    __shared__ short As[128 * 64];
    __shared__ short Bs[128 * 64];

    int bid = blockIdx.x;
    int cpx = gridDim.x >> 3;                 // 2048 % 8 == 0: bijective
    int swz = (bid & 7) * cpx + (bid >> 3);
    int nbn = N / 128;                        // 32
    int bm = swz / nbn, bn = swz % nbn;

    int tid = threadIdx.x;
    int wid = tid >> 6, lane = tid & 63;
    int wr = wid >> 1, wc = wid & 1;          // 2x2 waves -> 64x64 each
    int rowA0 = bm * 128, colB0 = bn * 128;

    f32x4 acc[4][4] = {};

    int ldrow = lane >> 3;                    // 0..7 rows within chunk
    int ldcol = (lane & 7) * 8;               // 0..56, 8 bf16 = 16B

    for (int k0 = 0; k0 < K; k0 += 64) {
        __syncthreads();                      // LDS reuse barrier
#pragma unroll
        for (int i = 0; i < 4; i++) {
            int chunk = wid * 4 + i;          // 16 chunks of 1KB each
            int r = chunk * 8 + ldrow;
            __builtin_amdgcn_global_load_lds(
                (const __attribute__((address_space(1))) void*)(A + (size_t)(rowA0 + r) * K + k0 + ldcol),
                (__attribute__((address_space(3))) void*)(&As[chunk * 512]), 16, 0, 0);
            __builtin_amdgcn_global_load_lds(
                (const __attribute__((address_space(1))) void*)(B + (size_t)(colB0 + r) * K + k0 + ldcol),
                (__attribute__((address_space(3))) void*)(&Bs[chunk * 512]), 16, 0, 0);
        }
        __syncthreads();                      // drains vmcnt before barrier
#pragma unroll
        for (int ks = 0; ks < 2; ks++) {
            bf16x8 af[4], bfr[4];
#pragma unroll
            for (int m = 0; m < 4; m++)
                af[m] = *(const bf16x8*)&As[(wr * 64 + m * 16 + (lane & 15)) * 64 + ks * 32 + (lane >> 4) * 8];
#pragma unroll
            for (int n = 0; n < 4; n++)
                bfr[n] = *(const bf16x8*)&Bs[(wc * 64 + n * 16 + (lane & 15)) * 64 + ks * 32 + (lane >> 4) * 8];
#pragma unroll
            for (int m = 0; m < 4; m++)
#pragma unroll
                for (int n = 0; n < 4; n++)
                    acc[m][n] = __builtin_amdgcn_mfma_f32_16x16x32_bf16(af[m], bfr[n], acc[m][n], 0, 0, 0);
        }
    }

    // epilogue: C/D layout col=lane&15, row=(lane>>4)*4+reg (m89-verified)
#pragma unroll
    for (int m = 0; m < 4; m++) {
        int row0 = rowA0 + wr * 64 + m * 16 + (lane >> 4) * 4;
#pragma unroll
        for (int n = 0; n < 4; n++) {
            int col = colB0 + wc * 64 + n * 16 + (lane & 15);
#pragma unroll
            for (int r = 0; r < 4; r++)
                C[(size_t)(row0 + r) * N + col] = acc[m][n][r];
        }
    }
}

// ---------------- launch ----------------

extern "C" void kernel_launch(void* const* d_in, const int* in_sizes, int n_in,
                              void* d_out, int out_size, void* d_ws, size_t ws_size,
                              hipStream_t stream) {
    const float* x          = (const float*)d_in[0];
    const float* weight     = (const float*)d_in[1];
    const float* new_weight = (const float*)d_in[2];
    const int* perm         = (const int*)d_in[3];
    const void* stored_raw  = (const void*)d_in[4];   // bool: bytes OR int32 (detected)
    const int* pb           = (const int*)d_in[5];
    float* out              = (float*)d_out;

    char* ws = (char*)d_ws;
    float* f             = (float*)(ws + 0);            // 16 KB
    unsigned char* mask  = (unsigned char*)(ws + 16384);// 4 KB
    int* counts          = (int*)(ws + 20480);          // 400 B
    int* flag            = (int*)(ws + 24576);          // 4 B
    float* fmask         = (float*)(ws + 28672);        // 16 KB
    unsigned char* smask = (unsigned char*)(ws + 65536);// 400 KB canonical stored
    unsigned short* xb   = (unsigned short*)(ws + (1 << 20));                          // 64 MB
    unsigned short* wb   = (unsigned short*)(ws + (1 << 20) + (size_t)M_DIM * D_DIM * 2); // 32 MB

    init_ws_kernel<<<1, 512, 0, stream>>>(f, counts);
    detect_mask_fmt_kernel<<<1, 256, 0, stream>>>((const unsigned*)stored_raw, flag);
    normalize_masks_kernel<<<256, 256, 0, stream>>>(stored_raw, flag, smask);
    reduce_mean_kernel<<<dim3(D_DIM / 256, 32), 256, 0, stream>>>(x, pb, f);
    topk_mask_kernel<<<1, 1024, 0, stream>>>(f, perm, mask);
    overlap_kernel<<<NMASKS, 256, 0, stream>>>(mask, smask, counts);
    gate_kernel<<<1, 256, 0, stream>>>(counts, smask, fmask);

    cvt_x_kernel<<<2048, 256, 0, stream>>>((const float4*)x, (ushort4*)xb,
                                           M_DIM * D_DIM / 4);
    cvt_w_kernel<<<2048, 256, 0, stream>>>((const float4*)weight, (const float4*)new_weight,
                                           (const float4*)fmask, (ushort4*)wb,
                                           O_DIM * D_DIM / 4);

    gemm_bf16_kernel<<<(M_DIM / 128) * (O_DIM / 128), 256, 0, stream>>>(xb, wb, out);
}

// Round 4
// 631.751 us; speedup vs baseline: 1.3850x; 1.3850x over previous
//
#include <hip/hip_runtime.h>
#include <stdint.h>

// Problem constants (match reference)
#define D_DIM 4096
#define O_DIM 4096
#define M_DIM 8192      // B*S = 4*2048
#define TOPK_K 2048
#define NMASKS 100

typedef __attribute__((ext_vector_type(8))) short bf16x8;
typedef __attribute__((ext_vector_type(4))) float f32x4;

__device__ __forceinline__ unsigned short f2bf(float f) {
    unsigned u = __float_as_uint(f);
    return (unsigned short)((u + 0x7FFFu + ((u >> 16) & 1u)) >> 16);
}

// ---------------- control path ----------------

__global__ void init_ws_kernel(float* f, int* counts) {
    int i = threadIdx.x;
    for (int j = i; j < D_DIM; j += blockDim.x) f[j] = 0.0f;
    if (i < NMASKS) counts[i] = 0;
}

// Detect stored_masks encoding: raw bytes (numpy bool) vs int32-widened.
__global__ void detect_mask_fmt_kernel(const unsigned* __restrict__ raw,
                                       int* __restrict__ flag) {
    __shared__ int anybig;
    if (threadIdx.x == 0) anybig = 0;
    __syncthreads();
    int big = 0;
    for (int i = threadIdx.x; i < 1024; i += blockDim.x)
        if (raw[i] > 1u) big = 1;
    if (big) atomicOr(&anybig, 1);
    __syncthreads();
    if (threadIdx.x == 0) *flag = anybig;   // 1 = byte-encoded, 0 = int32
}

__global__ void normalize_masks_kernel(const void* __restrict__ raw,
                                       const int* __restrict__ flag,
                                       unsigned char* __restrict__ out) {
    int n = NMASKS * D_DIM;
    int fmt = *flag;
    int stride = gridDim.x * blockDim.x;
    for (int i = blockIdx.x * blockDim.x + threadIdx.x; i < n; i += stride) {
        unsigned char v;
        if (fmt) v = ((const unsigned char*)raw)[i] ? 1 : 0;
        else     v = ((const int*)raw)[i] ? 1 : 0;
        out[i] = v;
    }
}

// f[d] = mean over rows 0..pb of x[0,:,d]
__global__ void reduce_mean_kernel(const float* __restrict__ x,
                                   const int* __restrict__ pb_ptr,
                                   float* __restrict__ f) {
    int d = blockIdx.x * blockDim.x + threadIdx.x;
    int rows = *pb_ptr + 1;
    float s = 0.0f;
    for (int r = blockIdx.y; r < rows; r += gridDim.y)
        s += x[(size_t)r * D_DIM + d];
    atomicAdd(&f[d], s * (1.0f / (float)rows));
}

// 256 threads: kth-largest |f| via binary search on float bits, wave-reduced
// counts (4 atomics/iter instead of 1024 serialized ones).
__global__ void topk_mask_kernel(const float* __restrict__ f,
                                 const int* __restrict__ perm,
                                 unsigned char* __restrict__ mask) {
    __shared__ unsigned bits[D_DIM];
    __shared__ int scount;
    int tid = threadIdx.x;
    for (int i = tid; i < D_DIM; i += 256) {
        bits[i] = __float_as_uint(f[i]) & 0x7FFFFFFFu;
        mask[i] = 0;
    }
    __syncthreads();
    unsigned lo = 0u, hi = 0x7F800001u;
    while (hi - lo > 1u) {
        unsigned mid = lo + ((hi - lo) >> 1);
        if (tid == 0) scount = 0;
        __syncthreads();
        int c = 0;
        for (int i = tid; i < D_DIM; i += 256) c += (bits[i] >= mid) ? 1 : 0;
        for (int off = 32; off; off >>= 1) c += __shfl_down(c, off);
        if ((tid & 63) == 0) atomicAdd(&scount, c);
        __syncthreads();
        if (scount >= TOPK_K) lo = mid; else hi = mid;
        __syncthreads();
    }
    for (int i = tid; i < D_DIM; i += 256)
        if (bits[i] >= lo) mask[perm[i]] = 1;
}

// one block per stored mask: popcount overlap
__global__ void overlap_kernel(const unsigned char* __restrict__ mask,
                               const unsigned char* __restrict__ stored,
                               int* __restrict__ counts) {
    int m = blockIdx.x;
    int tid = threadIdx.x;
    const uint4* a = (const uint4*)mask;
    const uint4* b = (const uint4*)(stored + (size_t)m * D_DIM);
    uint4 va = a[tid], vb = b[tid];
    int c = __popc((va.x & vb.x) & 0x01010101u) + __popc((va.y & vb.y) & 0x01010101u)
          + __popc((va.z & vb.z) & 0x01010101u) + __popc((va.w & vb.w) & 0x01010101u);
    for (int off = 32; off; off >>= 1) c += __shfl_down(c, off);
    if ((tid & 63) == 0) atomicAdd(&counts[m], c);
}

// single block: argmax over counts, gate, write final mask as float 0/1
__global__ void gate_kernel(const int* __restrict__ counts,
                            const unsigned char* __restrict__ stored,
                            float* __restrict__ fmask) {
    __shared__ int bestc, besti;
    if (threadIdx.x == 0) {
        int bc = -1, bi = 0;
        for (int m = 0; m < NMASKS; m++)
            if (counts[m] > bc) { bc = counts[m]; bi = m; }
        bestc = bc; besti = bi;
    }
    __syncthreads();
    bool gate = ((float)bestc / (float)TOPK_K) >= 0.6f;
    const unsigned char* sm = stored + (size_t)besti * D_DIM;
    for (int i = threadIdx.x; i < D_DIM; i += blockDim.x)
        fmask[i] = (gate && sm[i]) ? 1.0f : 0.0f;
}

// ---------------- conversions ----------------

__global__ void cvt_x_kernel(const float4* __restrict__ x,
                             ushort4* __restrict__ xb, int ngroups) {
    int stride = gridDim.x * blockDim.x;
    for (int j = blockIdx.x * blockDim.x + threadIdx.x; j < ngroups; j += stride) {
        float4 v = x[j];
        ushort4 o = { f2bf(v.x), f2bf(v.y), f2bf(v.z), f2bf(v.w) };
        xb[j] = o;
    }
}

__global__ void cvt_w_kernel(const float4* __restrict__ w,
                             const float4* __restrict__ nw,
                             const float4* __restrict__ fmask,
                             ushort4* __restrict__ wb, int ngroups) {
    int stride = gridDim.x * blockDim.x;
    for (int j = blockIdx.x * blockDim.x + threadIdx.x; j < ngroups; j += stride) {
        float4 a = w[j], b = nw[j], mk = fmask[j & (D_DIM / 4 - 1)];
        ushort4 o = { f2bf(a.x + mk.x * b.x), f2bf(a.y + mk.y * b.y),
                      f2bf(a.z + mk.z * b.z), f2bf(a.w + mk.w * b.w) };
        wb[j] = o;
    }
}

// ---------------- GEMM: C[m][n] = sum_k A[m][k]*B[n][k], bf16 in, f32 out ----
// 256x256 tile, BK=64, 8 waves (2Mx4N), 128KB double-buffered LDS.
// Staging: global_load_lds width=16, LINEAR LDS dest + pre-swizzled per-lane
// GLOBAL source col (rule #21/m173):  LDS[r][c'] = G[r][c' ^ ((r&7)<<4)].
// Reads apply the same XOR -> bank-conflict-free ds_read_b128 (T2).
// 4 phases/tile, prefetch issued p0/p1, one counted drain per tile (T3/T4),
// setprio around MFMA (T5), XCD-bijective swizzle (T1).

#define BM 256
#define BN 256
#define BK 64
#define NT (D_DIM / BK)   // 64

__global__ __launch_bounds__(512, 2) void gemm256_kernel(
    const unsigned short* __restrict__ A,   // [M][K]
    const unsigned short* __restrict__ B,   // [N][K]
    float* __restrict__ C) {
    constexpr int K = D_DIM, N_ = O_DIM;
    extern __shared__ char lds[];           // buf c at c*65536: A(32KB) then B(32KB)

    int bid = blockIdx.x;
    int cpx = gridDim.x >> 3;               // 512 % 8 == 0: bijective
    int swz = (bid & 7) * cpx + (bid >> 3);
    int nbn = N_ / BN;                      // 16
    int bm = swz / nbn, bn = swz % nbn;
    int rowA0 = bm * BM, colB0 = bn * BN;

    int tid = threadIdx.x;
    int lane = tid & 63, wid = tid >> 6;
    int wm = wid >> 2, wn = wid & 3;        // 2x4 waves: per-wave 128x64 output
    int l15 = lane & 15;
    int hi16 = (lane >> 4) << 4;
    int rsw = (lane & 7) << 4;              // read-side XOR: (row&7)<<4, row&7==lane&7
    int aBase = wm * 16384 + l15 * 128;     // A row wm*128 + m*16 + l15, 128B/row
    int bBase = wn * 8192 + l15 * 128;      // B row wn*64  + n*16 + l15

    // staging: per global_load_lds instr, wave writes 1KB linear (8 rows x 128B).
    // lane source: row_in_chunk = lane>>3, colByte = ((lane&7)^(lane>>3))<<4.
    unsigned gl = (unsigned)(lane >> 3) * (K * 2) + ((((lane & 7) ^ (lane >> 3)) << 4));
    const char* A0 = (const char*)(A + (size_t)rowA0 * K);
    const char* B0 = (const char*)(B + (size_t)colB0 * K);

#define GLDS(gbase, goff, lptr)                                             \
    __builtin_amdgcn_global_load_lds(                                       \
        (const __attribute__((address_space(1))) void*)((gbase) + (goff)),  \
        (__attribute__((address_space(3))) void*)(lptr), 16, 0, 0)

    // prologue: tile 0 -> buf0 (each wave: 4 A-chunks + 4 B-chunks of 1KB)
#pragma unroll
    for (int i = 0; i < 4; ++i) {
        int q = wid * 4 + i;                // chunk 0..31, rows 8q..8q+7
        GLDS(A0, (unsigned)q * 8u * (K * 2) + gl, lds + q * 1024);
        GLDS(B0, (unsigned)q * 8u * (K * 2) + gl, lds + 32768 + q * 1024);
    }
    asm volatile("s_waitcnt vmcnt(0)" ::: "memory");
    __builtin_amdgcn_s_barrier();

    f32x4 acc[8][4] = {};
    bf16x8 af[4][2], bv[2][2];

    for (int t = 0; t < NT; ++t) {
        const char* Ac = lds + (t & 1) * 65536;
        const char* Bc = Ac + 32768;
        char* An = lds + ((t + 1) & 1) * 65536;
        char* Bn = An + 32768;
        bool pf = (t + 1 < NT);
        unsigned kb = (unsigned)(t + 1) * (BK * 2);

#pragma unroll
        for (int p = 0; p < 4; ++p) {
            const int mg = p >> 1, ng = p & 1;   // quadrants (0,0)(0,1)(1,0)(1,1)
            if (ng == 0) {
#pragma unroll
                for (int im = 0; im < 4; ++im)
#pragma unroll
                    for (int kk = 0; kk < 2; ++kk)
                        af[im][kk] = *(const bf16x8*)(Ac + aBase + (mg * 4 + im) * 2048
                                                      + ((kk * 64 + hi16) ^ rsw));
            }
#pragma unroll
            for (int in = 0; in < 2; ++in)
#pragma unroll
                for (int kk = 0; kk < 2; ++kk)
                    bv[in][kk] = *(const bf16x8*)(Bc + bBase + (ng * 2 + in) * 2048
                                                  + ((kk * 64 + hi16) ^ rsw));
            // prefetch tile t+1: 4 instrs at p0 (A), 4 at p1 (B) -> long
            // issue->drain distance (~3 phases) before the tile-end vmcnt(0)
            if (pf && p == 0) {
#pragma unroll
                for (int i = 0; i < 4; ++i) {
                    int q = wid * 4 + i;
                    GLDS(A0, (unsigned)q * 8u * (K * 2) + gl + kb, An + q * 1024);
                }
            }
            if (pf && p == 1) {
#pragma unroll
                for (int i = 0; i < 4; ++i) {
                    int q = wid * 4 + i;
                    GLDS(B0, (unsigned)q * 8u * (K * 2) + gl + kb, Bn + q * 1024);
                }
            }
            __builtin_amdgcn_s_barrier();
            asm volatile("s_waitcnt lgkmcnt(0)" ::: "memory");
            __builtin_amdgcn_sched_barrier(0);   // rule #18: pin MFMA after the wait
            __builtin_amdgcn_s_setprio(1);
#pragma unroll
            for (int im = 0; im < 4; ++im)
#pragma unroll
                for (int in = 0; in < 2; ++in)
#pragma unroll
                    for (int kk = 0; kk < 2; ++kk)
                        acc[mg * 4 + im][ng * 2 + in] =
                            __builtin_amdgcn_mfma_f32_16x16x32_bf16(
                                af[im][kk], bv[in][kk],
                                acc[mg * 4 + im][ng * 2 + in], 0, 0, 0);
            __builtin_amdgcn_s_setprio(0);
            __builtin_amdgcn_s_barrier();
            __builtin_amdgcn_sched_barrier(0);
        }
        // tile boundary: own 8 prefetch loads must be in LDS before next reads
        asm volatile("s_waitcnt vmcnt(0)" ::: "memory");
        __builtin_amdgcn_s_barrier();
        __builtin_amdgcn_sched_barrier(0);
    }

    // epilogue: C/D layout col=lane&15, row=(lane>>4)*4+reg (m89-verified)
    int orow = rowA0 + wm * 128 + (lane >> 4) * 4;
    int ocol = colB0 + wn * 64 + l15;
#pragma unroll
    for (int m = 0; m < 8; ++m)
#pragma unroll
        for (int n = 0; n < 4; ++n)
#pragma unroll
            for (int r = 0; r < 4; ++r)
                C[(size_t)(orow + m * 16 + r) * N_ + ocol + n * 16] = acc[m][n][r];
#undef GLDS
}

// ---------------- launch ----------------

extern "C" void kernel_launch(void* const* d_in, const int* in_sizes, int n_in,
                              void* d_out, int out_size, void* d_ws, size_t ws_size,
                              hipStream_t stream) {
    const float* x          = (const float*)d_in[0];
    const float* weight     = (const float*)d_in[1];
    const float* new_weight = (const float*)d_in[2];
    const int* perm         = (const int*)d_in[3];
    const void* stored_raw  = (const void*)d_in[4];
    const int* pb           = (const int*)d_in[5];
    float* out              = (float*)d_out;

    char* ws = (char*)d_ws;
    float* f             = (float*)(ws + 0);
    unsigned char* mask  = (unsigned char*)(ws + 16384);
    int* counts          = (int*)(ws + 20480);
    int* flag            = (int*)(ws + 24576);
    float* fmask         = (float*)(ws + 28672);
    unsigned char* smask = (unsigned char*)(ws + 65536);
    unsigned short* xb   = (unsigned short*)(ws + (1 << 20));
    unsigned short* wb   = (unsigned short*)(ws + (1 << 20) + (size_t)M_DIM * D_DIM * 2);

    init_ws_kernel<<<1, 512, 0, stream>>>(f, counts);
    detect_mask_fmt_kernel<<<1, 256, 0, stream>>>((const unsigned*)stored_raw, flag);
    normalize_masks_kernel<<<256, 256, 0, stream>>>(stored_raw, flag, smask);
    reduce_mean_kernel<<<dim3(D_DIM / 256, 32), 256, 0, stream>>>(x, pb, f);
    topk_mask_kernel<<<1, 256, 0, stream>>>(f, perm, mask);
    overlap_kernel<<<NMASKS, 256, 0, stream>>>(mask, smask, counts);
    gate_kernel<<<1, 256, 0, stream>>>(counts, smask, fmask);

    cvt_x_kernel<<<2048, 256, 0, stream>>>((const float4*)x, (ushort4*)xb,
                                           M_DIM * D_DIM / 4);
    cvt_w_kernel<<<2048, 256, 0, stream>>>((const float4*)weight, (const float4*)new_weight,
                                           (const float4*)fmask, (ushort4*)wb,
                                           O_DIM * D_DIM / 4);

    (void)hipFuncSetAttribute(reinterpret_cast<const void*>(gemm256_kernel),
                              hipFuncAttributeMaxDynamicSharedMemorySize, 131072);
    gemm256_kernel<<<(M_DIM / BM) * (O_DIM / BN), 512, 131072, stream>>>(xb, wb, out);
}